// Round 12
// baseline (778.985 us; speedup 1.0000x reference)
//
#include <hip/hip_runtime.h>
#include <stdint.h>

#define B_  4
#define NQ_ 2048
#define NP_ 8192
#define D_  256
#define F_  40
#define K_  16

// ---------------- Kernel 1: hash codes -------------------------------------
// v10: proj scalar->VMEM-broadcast, cleanly. v9 (zero-barrier, per-lane
// global rows) REFUTED the barrier-lockstep theory: 50us, VALUBusy 12.6%.
// Invariant across the v5-v9 plateau = proj via readfirstlane+s_load:
// 1280 dwords/wave through the shallow scalar queue (lgkmcnt stall per
// SGPR batch, 80KB/CU thrashing K$). v8 tried to test this but asm("+v")
// laundering wrecked regalloc (VGPR 32, 1GB scratch). Here: NO inline asm,
// NO readfirstlane — pj derives from threadIdx (not provably uniform) so
// the compiler emits global_load_dwordx4 with identical per-lane addresses:
// single-line broadcast, L1/L2-hot (proj=40KB), deep vmcnt queue. Proj is
// register-staged in 16-dim sub-chunks (20 float4 = 80 VGPR, static
// indexing); launch_bounds(512,4) caps VGPR at 128. Staging structure = v7
// verbatim (4x64-dim chunks, double-buffered, 35.8KB LDS). Per-feature
// accumulation stays d=0..255 sequential (bit-exact).
__global__ __launch_bounds__(512, 4) void hash_kernel(
    const float* __restrict__ qp, const float* __restrict__ pp,
    const float* __restrict__ proj, uint64_t* __restrict__ qcodes,
    uint64_t* __restrict__ pcodes) {
  __shared__ float buf[2][64][68];          // 34.8 KB double buffer
  __shared__ unsigned short cbuf[64][8];    // 1 KB combine buffer
  int t = threadIdx.x;
  int v0 = blockIdx.x * 64;  // first vector in concat [queries; points] space
  bool isQ = v0 < B_ * NQ_;  // B*NQ = 8192 = 128 blocks: clean split
  const float* src =
      isQ ? (qp + (size_t)v0 * D_) : (pp + (size_t)(v0 - B_ * NQ_) * D_);
  const float4* src4 = (const float4*)src;  // rows are 1KB-aligned

  int lane = t & 63, w = t >> 6;  // 8 waves
  // NOTE: no readfirstlane — keep pj "divergent" so proj reads go VMEM.
  const float4* pj4 = (const float4*)(proj + (size_t)(w * 5) * 256);

  // Stage chunk c into buf[c&1]: 64 vec x 16 float4 = 1024 float4, 512 thr
  // -> 2 each. idx=i*512+t: v=idx>>4, f4=idx&15.
#define STAGE(c)                                              \
  {                                                           \
    _Pragma("unroll")                                         \
    for (int i = 0; i < 2; ++i) {                             \
      int idx = i * 512 + t;                                  \
      int v = idx >> 4, f4 = idx & 15;                        \
      float4 x = src4[v * 64 + (c) * 16 + f4];                \
      *(float4*)&buf[(c) & 1][v][4 * f4] = x;                 \
    }                                                         \
  }

  float acc[5];
#pragma unroll
  for (int f = 0; f < 5; ++f) acc[f] = 0.0f;

  STAGE(0);
  __syncthreads();
#pragma unroll
  for (int c = 0; c < 4; ++c) {
    if (c < 3) STAGE(c + 1);  // overlaps compute(c); LDS write drains at bar
    const float4* row4 = (const float4*)&buf[c & 1][lane][0];
#pragma unroll
    for (int s = 0; s < 4; ++s) {  // 16-dim proj sub-chunks
      // Register-stage proj[f][c*64+s*16 .. +15]: 20 broadcast VMEM loads.
      float4 pr0[4], pr1[4], pr2[4], pr3[4], pr4[4];
#pragma unroll
      for (int j = 0; j < 4; ++j) {
        int off = c * 16 + s * 4 + j;  // float4 index within a proj row
        pr0[j] = pj4[0 * 64 + off];
        pr1[j] = pj4[1 * 64 + off];
        pr2[j] = pj4[2 * 64 + off];
        pr3[j] = pj4[3 * 64 + off];
        pr4[j] = pj4[4 * 64 + off];
      }
#pragma unroll
      for (int j = 0; j < 4; ++j) {
        float4 x4 = row4[s * 4 + j];  // ds_read_b128
        // Per-feature order x,y,z,w with j,s,c ascending == d 0..255.
        acc[0] = fmaf(x4.x, pr0[j].x, acc[0]);
        acc[0] = fmaf(x4.y, pr0[j].y, acc[0]);
        acc[0] = fmaf(x4.z, pr0[j].z, acc[0]);
        acc[0] = fmaf(x4.w, pr0[j].w, acc[0]);
        acc[1] = fmaf(x4.x, pr1[j].x, acc[1]);
        acc[1] = fmaf(x4.y, pr1[j].y, acc[1]);
        acc[1] = fmaf(x4.z, pr1[j].z, acc[1]);
        acc[1] = fmaf(x4.w, pr1[j].w, acc[1]);
        acc[2] = fmaf(x4.x, pr2[j].x, acc[2]);
        acc[2] = fmaf(x4.y, pr2[j].y, acc[2]);
        acc[2] = fmaf(x4.z, pr2[j].z, acc[2]);
        acc[2] = fmaf(x4.w, pr2[j].w, acc[2]);
        acc[3] = fmaf(x4.x, pr3[j].x, acc[3]);
        acc[3] = fmaf(x4.y, pr3[j].y, acc[3]);
        acc[3] = fmaf(x4.z, pr3[j].z, acc[3]);
        acc[3] = fmaf(x4.w, pr3[j].w, acc[3]);
        acc[4] = fmaf(x4.x, pr4[j].x, acc[4]);
        acc[4] = fmaf(x4.y, pr4[j].y, acc[4]);
        acc[4] = fmaf(x4.z, pr4[j].z, acc[4]);
        acc[4] = fmaf(x4.w, pr4[j].w, acc[4]);
      }
    }
    __syncthreads();  // compute(c) readers done + stage(c+1) writes landed
  }
#undef STAGE

  unsigned bits = 0;
#pragma unroll
  for (int f = 0; f < 5; ++f)
    if (acc[f] > 0.0f) bits |= 1u << f;

  // Combine the 8 waves' 5-bit chunks per vector.
  cbuf[lane][w] = (unsigned short)bits;
  __syncthreads();
  if (w == 0) {
    uint64_t code = 0;
#pragma unroll
    for (int j = 0; j < 8; ++j)
      code |= (uint64_t)cbuf[lane][j] << (5 * j);
    int gv = v0 + lane;
    if (isQ) qcodes[gv] = code;
    else pcodes[gv - B_ * NQ_] = code;
  }
}

// ---------------- Kernel 2: exact top-16 by (dist, index) -------------------
// v4 (unchanged, HW-verified absmax 0.0): nibble cache in LDS (4KB/wave),
// codes streamed from global (64KB/batch, L2-resident), zero __syncthreads,
// launch_bounds(512,8) -> 4 blocks/CU = 32 waves/CU.
__global__ __launch_bounds__(512, 8) void select_kernel(
    const uint64_t* __restrict__ qcodes, const uint64_t* __restrict__ pcodes,
    float* __restrict__ outIdx, float* __restrict__ outDist) {
  __shared__ unsigned nib[8 * 1024];  // 32 KB: 8 waves x 4KB nibble cache
  __shared__ unsigned keybuf[8][K_];

  int tid = threadIdx.x;
  int w = tid >> 6, lane = tid & 63;
  int qg = blockIdx.x * 8 + w;  // global query id
  int bb = blockIdx.x >> 8;     // 256 blocks per batch
  const ulonglong2* pb2 = (const ulonglong2*)(pcodes + (size_t)bb * NP_);
  uint64_t qc = qcodes[qg];
  unsigned* nibw = nib + w * 1024;
  const uint64_t M = 0x00FF00FF00FF00FFull;

  // ---- Pass 1: stream codes from L2; nibble cache + merged-bin hist ----
  uint64_t cf = 0;
  unsigned accum = 0;
#pragma unroll 4
  for (int j2 = 0; j2 < 64; ++j2) {
    ulonglong2 pc = pb2[j2 * 64 + lane];  // coalesced 16B, L2-hot
    unsigned d0 = (unsigned)__popcll(qc ^ pc.x);
    unsigned d1 = (unsigned)__popcll(qc ^ pc.y);
    unsigned c0 = d0 < 15u ? d0 : 15u;
    unsigned c1 = d1 < 15u ? d1 : 15u;
    accum |= (c0 | (c1 << 4)) << (8 * (j2 & 3));
    int r0 = (int)d0 - 8; r0 = r0 < 0 ? 0 : (r0 > 7 ? 7 : r0);  // v_med3
    int r1 = (int)d1 - 8; r1 = r1 < 0 ? 0 : (r1 > 7 ? 7 : r1);
    cf += (1ull << (r0 << 3)) + (1ull << (r1 << 3));  // bytes <=128: safe
    if ((j2 & 3) == 3) {
      nibw[lane + 64 * (j2 >> 2)] = accum;  // bank lane%32: 2-way, free
      accum = 0;
    }
  }
  uint64_t e = cf & M, o = (cf >> 8) & M;
#pragma unroll
  for (int s = 1; s < 64; s <<= 1) {
    e += __shfl_xor(e, s);
    o += __shfl_xor(o, s);
  }

  int t = 0;
  unsigned n_lt = 0;
  int rfound = -1;
  {
    unsigned cum = 0;
#pragma unroll
    for (int r = 0; r < 8; ++r) {
      unsigned c = (unsigned)(((r & 1) ? o : e) >> ((r >> 1) * 16)) & 0xFFFFu;
      if (rfound < 0 && cum + c >= K_) { rfound = r; t = 8 + r; n_lt = cum; }
      cum += c;
    }
  }
  uint64_t lmask = (1ull << lane) - 1;

  if (rfound >= 1 && rfound <= 6) {
    // ---- Pass 3 (fast): LDS nibble scan, pair-ordered collection ----
    unsigned r_need = K_ - n_lt;
    unsigned cl = 0, ce = 0;
    unsigned ut = (unsigned)t;
#pragma unroll 4
    for (int k = 0; k < 16; ++k) {
      unsigned dw = nibw[lane + 64 * k];
#pragma unroll
      for (int b = 0; b < 4; ++b) {
        unsigned d0 = (dw >> (8 * b)) & 0xFu;
        unsigned d1 = (dw >> (8 * b + 4)) & 0xFu;
        int p0 = (4 * k + b) * 128 + 2 * lane;
        uint64_t m0 = __ballot(d0 < ut);
        uint64_t m1 = __ballot(d1 < ut);
        if (m0 | m1) {
          unsigned base = cl + (unsigned)__popcll(m0 & lmask) +
                          (unsigned)__popcll(m1 & lmask);
          if (d0 < ut) keybuf[w][base] = (d0 << 13) | (unsigned)p0;
          if (d1 < ut)
            keybuf[w][base + (unsigned)((m0 >> lane) & 1)] =
                (d1 << 13) | (unsigned)(p0 + 1);
          cl += (unsigned)__popcll(m0) + (unsigned)__popcll(m1);
        }
        if (ce < r_need) {  // wave-uniform: skipped once eq quota filled
          uint64_t q0 = __ballot(d0 == ut);
          uint64_t q1 = __ballot(d1 == ut);
          if (q0 | q1) {
            unsigned b2 = ce + (unsigned)__popcll(q0 & lmask) +
                          (unsigned)__popcll(q1 & lmask);
            unsigned pos1 = b2 + (unsigned)((q0 >> lane) & 1);
            if (d0 == ut && b2 < r_need)
              keybuf[w][n_lt + b2] = (ut << 13) | (unsigned)p0;
            if (d1 == ut && pos1 < r_need)
              keybuf[w][n_lt + pos1] = (ut << 13) | (unsigned)(p0 + 1);
            ce += (unsigned)__popcll(q0) + (unsigned)__popcll(q1);
          }
        }
      }
    }
  } else {
    // ---- Exact fallback (cold, prob ~0): global re-scan, 3-pass ----
    const uint64_t* pbl = pcodes + (size_t)bb * NP_;
    uint64_t c8 = 0;
#pragma unroll 4
    for (int j = 0; j < 64; ++j) {
      ulonglong2 pc = pb2[j * 64 + lane];
      int d0 = __popcll(qc ^ pc.x);
      int d1 = __popcll(qc ^ pc.y);
      c8 += (1ull << (d0 & 56)) + (1ull << (d1 & 56));  // (d>>3)*8 == d&56
    }
    uint64_t e2 = c8 & M, o2 = (c8 >> 8) & M;
#pragma unroll
    for (int s = 1; s < 64; s <<= 1) {
      e2 += __shfl_xor(e2, s);
      o2 += __shfl_xor(o2, s);
    }
    int Bb = 0;
    unsigned nbefore = 0, cum = 0;
    bool found = false;
#pragma unroll
    for (int k2 = 0; k2 < 6; ++k2) {
      unsigned c = (unsigned)(((k2 & 1) ? o2 : e2) >> ((k2 >> 1) * 16)) & 0xFFFFu;
      if (!found && cum + c >= K_) { Bb = k2; nbefore = cum; found = true; }
      cum += c;
    }
    int base = Bb * 8;
    uint64_t cff = 0;
#pragma unroll 4
    for (int j = 0; j < 64; ++j) {
      ulonglong2 pc = pb2[j * 64 + lane];
      unsigned r0 = (unsigned)(__popcll(qc ^ pc.x) - base);
      unsigned r1 = (unsigned)(__popcll(qc ^ pc.y) - base);
      if (r0 < 8u) cff += 1ull << (r0 << 3);
      if (r1 < 8u) cff += 1ull << (r1 << 3);
    }
    uint64_t ef = cff & M, of = (cff >> 8) & M;
#pragma unroll
    for (int s = 1; s < 64; s <<= 1) {
      ef += __shfl_xor(ef, s);
      of += __shfl_xor(of, s);
    }
    unsigned cum2 = nbefore;
    bool f2 = false;
#pragma unroll
    for (int r = 0; r < 8; ++r) {
      unsigned c = (unsigned)(((r & 1) ? of : ef) >> ((r >> 1) * 16)) & 0xFFFFu;
      if (!f2 && cum2 + c >= K_) { t = base + r; n_lt = cum2; f2 = true; }
      cum2 += c;
    }
    unsigned r_need = K_ - n_lt;
    unsigned cl = 0, ce = 0;
    for (int j = 0; j < 128; ++j) {
      int p = j * 64 + lane;
      int d = __popcll(qc ^ pbl[p]);
      if (__any(d <= t)) {
        bool blt = (d < t), beq = (d == t);
        uint64_t mlt = __ballot(blt), meq = __ballot(beq);
        if (blt)
          keybuf[w][cl + (unsigned)__popcll(mlt & lmask)] =
              ((unsigned)d << 13) | (unsigned)p;
        if (beq) {
          unsigned pos = ce + (unsigned)__popcll(meq & lmask);
          if (pos < r_need)
            keybuf[w][n_lt + pos] = ((unsigned)d << 13) | (unsigned)p;
        }
        cl += (unsigned)__popcll(mlt);
        ce += (unsigned)__popcll(meq);
      }
    }
  }

  // ---- rank-sort the 16 keys (distinct: idx embedded) and emit ----
  // keybuf[w] written and read by the SAME wave: no block sync needed.
  if (lane < K_) {
    unsigned my = keybuf[w][lane];
    int rank = 0;
#pragma unroll
    for (int jj = 0; jj < K_; ++jj) rank += (keybuf[w][jj] < my) ? 1 : 0;
    int off = qg * K_ + rank;
    outIdx[off]  = (float)(my & 8191u);  // index
    outDist[off] = (float)(my >> 13);    // distance
  }
}

extern "C" void kernel_launch(void* const* d_in, const int* in_sizes, int n_in,
                              void* d_out, int out_size, void* d_ws, size_t ws_size,
                              hipStream_t stream) {
  const float* qp   = (const float*)d_in[0];
  const float* pp   = (const float*)d_in[1];
  const float* proj = (const float*)d_in[2];
  // d_in[3] is k (always 16) — hardcoded.

  uint64_t* pcodes = (uint64_t*)d_ws;            // B*NP u64
  uint64_t* qcodes = pcodes + (size_t)B_ * NP_;  // B*NQ u64

  float* outIdx  = (float*)d_out;                   // B*NQ*K indices (as float)
  float* outDist = outIdx + (size_t)B_ * NQ_ * K_;  // B*NQ*K distances

  int total_vecs = B_ * (NQ_ + NP_);  // 40960
  hash_kernel<<<total_vecs / 64, 512, 0, stream>>>(qp, pp, proj, qcodes, pcodes);
  select_kernel<<<B_ * NQ_ / 8, 512, 0, stream>>>(qcodes, pcodes, outIdx, outDist);
}

// Round 13
// 186.723 us; speedup vs baseline: 4.1719x; 4.1719x over previous
//
#include <hip/hip_runtime.h>
#include <stdint.h>

#define B_  4
#define NQ_ 2048
#define NP_ 8192
#define D_  256
#define F_  40
#define K_  16

// ---------------- Kernel 1: hash codes -------------------------------------
// v11: proj in LDS, read as wave-uniform ds_read_b128 BROADCASTS.
// History: scalar proj (readfirstlane+s_load) = 34-50us plateau (v5-v7,v9);
// VGPR attempts spilled (v8: asm-launder, VGPR 32, 1GB scratch; v10:
// reg-stage, VGPR 64 cap, 1.3GB scratch). LDS broadcast needs NO registers
// beyond one float4 and NO scalar queue: stage all 40KB of proj once per
// block (coalesced, 5 float4/thread), then proj reads are uniform-address
// ds_read_b128 (HW broadcast, conflict-free, ~1-2cyc). Live VGPRs ~45 < 64
// ceiling. Vector staging = v7's chunked double-buffer (4 x 64-dim chunks).
// LDS 75KB -> 2 blocks/CU = 16 waves/CU (LDS-bound; VGPR headroom free).
// Accumulation d=0..255 sequential per feature (bit-exact, as all passing
// rounds). 512 thr, 8 waves x 5 features, lane = vector.
__global__ __launch_bounds__(512) void hash_kernel(
    const float* __restrict__ qp, const float* __restrict__ pp,
    const float* __restrict__ proj, uint64_t* __restrict__ qcodes,
    uint64_t* __restrict__ pcodes) {
  __shared__ float buf[2][64][68];        // 34.8 KB vector double buffer
  __shared__ float psh[F_ * 256];         // 40 KB proj (f-major, linear)
  __shared__ unsigned short cbuf[64][8];  // 1 KB combine buffer
  int t = threadIdx.x;
  int v0 = blockIdx.x * 64;  // first vector in concat [queries; points] space
  bool isQ = v0 < B_ * NQ_;  // B*NQ = 8192 = 128 blocks: clean split
  const float* src =
      isQ ? (qp + (size_t)v0 * D_) : (pp + (size_t)(v0 - B_ * NQ_) * D_);
  const float4* src4 = (const float4*)src;  // rows are 1KB-aligned

  int lane = t & 63, w = t >> 6;  // 8 waves
  int fb = w * 5;                 // this wave's first feature

  // Stage chunk c into buf[c&1]: 64 vec x 16 float4 = 1024 float4, 512 thr
  // -> 2 each. idx=i*512+t: v=idx>>4, f4=idx&15.
#define STAGE(c)                                              \
  {                                                           \
    _Pragma("unroll")                                         \
    for (int i = 0; i < 2; ++i) {                             \
      int idx = i * 512 + t;                                  \
      int v = idx >> 4, f4 = idx & 15;                        \
      float4 x = src4[v * 64 + (c) * 16 + f4];                \
      *(float4*)&buf[(c) & 1][v][4 * f4] = x;                 \
    }                                                         \
  }

  // Stage all of proj: 2560 float4, 512 threads -> 5 each, coalesced.
  {
    const float4* proj4 = (const float4*)proj;
    float4* psh4 = (float4*)psh;
#pragma unroll
    for (int i = 0; i < 5; ++i) psh4[i * 512 + t] = proj4[i * 512 + t];
  }

  float acc[5];
#pragma unroll
  for (int f = 0; f < 5; ++f) acc[f] = 0.0f;

  STAGE(0);
  __syncthreads();
#pragma unroll
  for (int c = 0; c < 4; ++c) {
    if (c < 3) STAGE(c + 1);  // overlaps compute(c); drains at the barrier
    const float4* row4 = (const float4*)&buf[c & 1][lane][0];
#pragma unroll
    for (int d4 = 0; d4 < 16; ++d4) {
      float4 x4 = row4[d4];  // per-lane ds_read_b128
#pragma unroll
      for (int f = 0; f < 5; ++f) {
        // Wave-uniform address -> LDS broadcast read, conflict-free.
        float4 p = *(const float4*)&psh[(fb + f) * 256 + c * 64 + 4 * d4];
        // x,y,z,w with d4 then c ascending == d 0..255 per feature.
        acc[f] = fmaf(x4.x, p.x, acc[f]);
        acc[f] = fmaf(x4.y, p.y, acc[f]);
        acc[f] = fmaf(x4.z, p.z, acc[f]);
        acc[f] = fmaf(x4.w, p.w, acc[f]);
      }
    }
    __syncthreads();  // compute(c) readers done + stage(c+1) writes landed
  }
#undef STAGE

  unsigned bits = 0;
#pragma unroll
  for (int f = 0; f < 5; ++f)
    if (acc[f] > 0.0f) bits |= 1u << f;

  // Combine the 8 waves' 5-bit chunks per vector.
  cbuf[lane][w] = (unsigned short)bits;
  __syncthreads();
  if (w == 0) {
    uint64_t code = 0;
#pragma unroll
    for (int j = 0; j < 8; ++j)
      code |= (uint64_t)cbuf[lane][j] << (5 * j);
    int gv = v0 + lane;
    if (isQ) qcodes[gv] = code;
    else pcodes[gv - B_ * NQ_] = code;
  }
}

// ---------------- Kernel 2: exact top-16 by (dist, index) -------------------
// v4 (unchanged, HW-verified absmax 0.0): nibble cache in LDS (4KB/wave),
// codes streamed from global (64KB/batch, L2-resident), zero __syncthreads,
// launch_bounds(512,8) -> 4 blocks/CU = 32 waves/CU.
__global__ __launch_bounds__(512, 8) void select_kernel(
    const uint64_t* __restrict__ qcodes, const uint64_t* __restrict__ pcodes,
    float* __restrict__ outIdx, float* __restrict__ outDist) {
  __shared__ unsigned nib[8 * 1024];  // 32 KB: 8 waves x 4KB nibble cache
  __shared__ unsigned keybuf[8][K_];

  int tid = threadIdx.x;
  int w = tid >> 6, lane = tid & 63;
  int qg = blockIdx.x * 8 + w;  // global query id
  int bb = blockIdx.x >> 8;     // 256 blocks per batch
  const ulonglong2* pb2 = (const ulonglong2*)(pcodes + (size_t)bb * NP_);
  uint64_t qc = qcodes[qg];
  unsigned* nibw = nib + w * 1024;
  const uint64_t M = 0x00FF00FF00FF00FFull;

  // ---- Pass 1: stream codes from L2; nibble cache + merged-bin hist ----
  uint64_t cf = 0;
  unsigned accum = 0;
#pragma unroll 4
  for (int j2 = 0; j2 < 64; ++j2) {
    ulonglong2 pc = pb2[j2 * 64 + lane];  // coalesced 16B, L2-hot
    unsigned d0 = (unsigned)__popcll(qc ^ pc.x);
    unsigned d1 = (unsigned)__popcll(qc ^ pc.y);
    unsigned c0 = d0 < 15u ? d0 : 15u;
    unsigned c1 = d1 < 15u ? d1 : 15u;
    accum |= (c0 | (c1 << 4)) << (8 * (j2 & 3));
    int r0 = (int)d0 - 8; r0 = r0 < 0 ? 0 : (r0 > 7 ? 7 : r0);  // v_med3
    int r1 = (int)d1 - 8; r1 = r1 < 0 ? 0 : (r1 > 7 ? 7 : r1);
    cf += (1ull << (r0 << 3)) + (1ull << (r1 << 3));  // bytes <=128: safe
    if ((j2 & 3) == 3) {
      nibw[lane + 64 * (j2 >> 2)] = accum;  // bank lane%32: 2-way, free
      accum = 0;
    }
  }
  uint64_t e = cf & M, o = (cf >> 8) & M;
#pragma unroll
  for (int s = 1; s < 64; s <<= 1) {
    e += __shfl_xor(e, s);
    o += __shfl_xor(o, s);
  }

  int t = 0;
  unsigned n_lt = 0;
  int rfound = -1;
  {
    unsigned cum = 0;
#pragma unroll
    for (int r = 0; r < 8; ++r) {
      unsigned c = (unsigned)(((r & 1) ? o : e) >> ((r >> 1) * 16)) & 0xFFFFu;
      if (rfound < 0 && cum + c >= K_) { rfound = r; t = 8 + r; n_lt = cum; }
      cum += c;
    }
  }
  uint64_t lmask = (1ull << lane) - 1;

  if (rfound >= 1 && rfound <= 6) {
    // ---- Pass 3 (fast): LDS nibble scan, pair-ordered collection ----
    unsigned r_need = K_ - n_lt;
    unsigned cl = 0, ce = 0;
    unsigned ut = (unsigned)t;
#pragma unroll 4
    for (int k = 0; k < 16; ++k) {
      unsigned dw = nibw[lane + 64 * k];
#pragma unroll
      for (int b = 0; b < 4; ++b) {
        unsigned d0 = (dw >> (8 * b)) & 0xFu;
        unsigned d1 = (dw >> (8 * b + 4)) & 0xFu;
        int p0 = (4 * k + b) * 128 + 2 * lane;
        uint64_t m0 = __ballot(d0 < ut);
        uint64_t m1 = __ballot(d1 < ut);
        if (m0 | m1) {
          unsigned base = cl + (unsigned)__popcll(m0 & lmask) +
                          (unsigned)__popcll(m1 & lmask);
          if (d0 < ut) keybuf[w][base] = (d0 << 13) | (unsigned)p0;
          if (d1 < ut)
            keybuf[w][base + (unsigned)((m0 >> lane) & 1)] =
                (d1 << 13) | (unsigned)(p0 + 1);
          cl += (unsigned)__popcll(m0) + (unsigned)__popcll(m1);
        }
        if (ce < r_need) {  // wave-uniform: skipped once eq quota filled
          uint64_t q0 = __ballot(d0 == ut);
          uint64_t q1 = __ballot(d1 == ut);
          if (q0 | q1) {
            unsigned b2 = ce + (unsigned)__popcll(q0 & lmask) +
                          (unsigned)__popcll(q1 & lmask);
            unsigned pos1 = b2 + (unsigned)((q0 >> lane) & 1);
            if (d0 == ut && b2 < r_need)
              keybuf[w][n_lt + b2] = (ut << 13) | (unsigned)p0;
            if (d1 == ut && pos1 < r_need)
              keybuf[w][n_lt + pos1] = (ut << 13) | (unsigned)(p0 + 1);
            ce += (unsigned)__popcll(q0) + (unsigned)__popcll(q1);
          }
        }
      }
    }
  } else {
    // ---- Exact fallback (cold, prob ~0): global re-scan, 3-pass ----
    const uint64_t* pbl = pcodes + (size_t)bb * NP_;
    uint64_t c8 = 0;
#pragma unroll 4
    for (int j = 0; j < 64; ++j) {
      ulonglong2 pc = pb2[j * 64 + lane];
      int d0 = __popcll(qc ^ pc.x);
      int d1 = __popcll(qc ^ pc.y);
      c8 += (1ull << (d0 & 56)) + (1ull << (d1 & 56));  // (d>>3)*8 == d&56
    }
    uint64_t e2 = c8 & M, o2 = (c8 >> 8) & M;
#pragma unroll
    for (int s = 1; s < 64; s <<= 1) {
      e2 += __shfl_xor(e2, s);
      o2 += __shfl_xor(o2, s);
    }
    int Bb = 0;
    unsigned nbefore = 0, cum = 0;
    bool found = false;
#pragma unroll
    for (int k2 = 0; k2 < 6; ++k2) {
      unsigned c = (unsigned)(((k2 & 1) ? o2 : e2) >> ((k2 >> 1) * 16)) & 0xFFFFu;
      if (!found && cum + c >= K_) { Bb = k2; nbefore = cum; found = true; }
      cum += c;
    }
    int base = Bb * 8;
    uint64_t cff = 0;
#pragma unroll 4
    for (int j = 0; j < 64; ++j) {
      ulonglong2 pc = pb2[j * 64 + lane];
      unsigned r0 = (unsigned)(__popcll(qc ^ pc.x) - base);
      unsigned r1 = (unsigned)(__popcll(qc ^ pc.y) - base);
      if (r0 < 8u) cff += 1ull << (r0 << 3);
      if (r1 < 8u) cff += 1ull << (r1 << 3);
    }
    uint64_t ef = cff & M, of = (cff >> 8) & M;
#pragma unroll
    for (int s = 1; s < 64; s <<= 1) {
      ef += __shfl_xor(ef, s);
      of += __shfl_xor(of, s);
    }
    unsigned cum2 = nbefore;
    bool f2 = false;
#pragma unroll
    for (int r = 0; r < 8; ++r) {
      unsigned c = (unsigned)(((r & 1) ? of : ef) >> ((r >> 1) * 16)) & 0xFFFFu;
      if (!f2 && cum2 + c >= K_) { t = base + r; n_lt = cum2; f2 = true; }
      cum2 += c;
    }
    unsigned r_need = K_ - n_lt;
    unsigned cl = 0, ce = 0;
    for (int j = 0; j < 128; ++j) {
      int p = j * 64 + lane;
      int d = __popcll(qc ^ pbl[p]);
      if (__any(d <= t)) {
        bool blt = (d < t), beq = (d == t);
        uint64_t mlt = __ballot(blt), meq = __ballot(beq);
        if (blt)
          keybuf[w][cl + (unsigned)__popcll(mlt & lmask)] =
              ((unsigned)d << 13) | (unsigned)p;
        if (beq) {
          unsigned pos = ce + (unsigned)__popcll(meq & lmask);
          if (pos < r_need)
            keybuf[w][n_lt + pos] = ((unsigned)d << 13) | (unsigned)p;
        }
        cl += (unsigned)__popcll(mlt);
        ce += (unsigned)__popcll(meq);
      }
    }
  }

  // ---- rank-sort the 16 keys (distinct: idx embedded) and emit ----
  // keybuf[w] written and read by the SAME wave: no block sync needed.
  if (lane < K_) {
    unsigned my = keybuf[w][lane];
    int rank = 0;
#pragma unroll
    for (int jj = 0; jj < K_; ++jj) rank += (keybuf[w][jj] < my) ? 1 : 0;
    int off = qg * K_ + rank;
    outIdx[off]  = (float)(my & 8191u);  // index
    outDist[off] = (float)(my >> 13);    // distance
  }
}

extern "C" void kernel_launch(void* const* d_in, const int* in_sizes, int n_in,
                              void* d_out, int out_size, void* d_ws, size_t ws_size,
                              hipStream_t stream) {
  const float* qp   = (const float*)d_in[0];
  const float* pp   = (const float*)d_in[1];
  const float* proj = (const float*)d_in[2];
  // d_in[3] is k (always 16) — hardcoded.

  uint64_t* pcodes = (uint64_t*)d_ws;            // B*NP u64
  uint64_t* qcodes = pcodes + (size_t)B_ * NP_;  // B*NQ u64

  float* outIdx  = (float*)d_out;                   // B*NQ*K indices (as float)
  float* outDist = outIdx + (size_t)B_ * NQ_ * K_;  // B*NQ*K distances

  int total_vecs = B_ * (NQ_ + NP_);  // 40960
  hash_kernel<<<total_vecs / 64, 512, 0, stream>>>(qp, pp, proj, qcodes, pcodes);
  select_kernel<<<B_ * NQ_ / 8, 512, 0, stream>>>(qcodes, pcodes, outIdx, outDist);
}

// Round 14
// 137.532 us; speedup vs baseline: 5.6640x; 1.3577x over previous
//
#include <hip/hip_runtime.h>
#include <stdint.h>

#define B_  4
#define NQ_ 2048
#define NP_ 8192
#define D_  256
#define F_  40
#define K_  16

// ---------------- Kernel 1: hash codes -------------------------------------
// v5 (REVERT to best-verified, round-6 bench total 139.06us): 512-thread
// blocks (8 waves), wave w computes features [5w,5w+5) for vector = lane;
// 64x257 fp32 tile (read bank 2-way = free) -> 2 blocks/CU x 8 waves =
// 4 waves/SIMD. Staging: 8 float4 loads/thread (wave covers one row/iter,
// coalesced 1KB), all 8 in flight. Proj via readfirstlane+s_load (scalar).
// Post-v13 ledger: every alternative tried was WORSE — v6 b128 reads 42.8,
// v7 chunked-dbuf 4blk/CU ~38, v9 no-LDS 50, v8/v10 VGPR-proj spilled
// (1GB+ scratch), v11 LDS-broadcast-proj 80 + spill. v5 stands.
// Accumulation sequential d=0..255 per feature (bit-exact); bit order is a
// fixed permutation applied identically to q/p codes -> distances invariant.
__global__ __launch_bounds__(512) void hash_kernel(
    const float* __restrict__ qp, const float* __restrict__ pp,
    const float* __restrict__ proj, uint64_t* __restrict__ qcodes,
    uint64_t* __restrict__ pcodes) {
  __shared__ float tile[64 * 257];
  int t = threadIdx.x;
  int v0 = blockIdx.x * 64;  // first vector in concat [queries; points] space
  bool isQ = v0 < B_ * NQ_;  // B*NQ = 8192 = 128 blocks: clean split
  const float* src =
      isQ ? (qp + (size_t)v0 * D_) : (pp + (size_t)(v0 - B_ * NQ_) * D_);
  const float4* src4 = (const float4*)src;  // rows are 1KB-aligned

  // Stage: iter i, thread t covers float4 #(i*512+t) -> row i*8 + (t>>6)
  // (wave-uniform), cols 4*(t&63).. +3. 8 dwordx4 in flight per thread.
#pragma unroll
  for (int i = 0; i < 8; ++i) {
    float4 x = src4[i * 512 + t];
    int r = i * 8 + (t >> 6);
    int c = 4 * (t & 63);
    tile[r * 257 + c + 0] = x.x;  // stride 257 breaks 16B align: b32 writes
    tile[r * 257 + c + 1] = x.y;
    tile[r * 257 + c + 2] = x.z;
    tile[r * 257 + c + 3] = x.w;
  }
  __syncthreads();

  int lane = t & 63, w = t >> 6;  // 8 waves
  int fbase = __builtin_amdgcn_readfirstlane(w * 5);
  const float* pj = proj + (size_t)fbase * 256;

  float acc[5];
#pragma unroll
  for (int f = 0; f < 5; ++f) acc[f] = 0.0f;
#pragma unroll 4
  for (int d = 0; d < 256; ++d) {
    float x = tile[lane * 257 + d];  // bank (lane+d)%32 -> 2-way, free
#pragma unroll
    for (int f = 0; f < 5; ++f) acc[f] = fmaf(x, pj[f * 256 + d], acc[f]);
  }
  unsigned bits = 0;
#pragma unroll
  for (int f = 0; f < 5; ++f)
    if (acc[f] > 0.0f) bits |= 1u << f;

  // Combine the 8 waves' 5-bit chunks per vector (reuse tile LDS).
  __syncthreads();
  unsigned short* cb = (unsigned short*)tile;
  cb[lane * 8 + w] = (unsigned short)bits;
  __syncthreads();
  if (w == 0) {
    uint64_t code = 0;
#pragma unroll
    for (int j = 0; j < 8; ++j)
      code |= (uint64_t)cb[lane * 8 + j] << (5 * j);
    int gv = v0 + lane;
    if (isQ) qcodes[gv] = code;
    else pcodes[gv - B_ * NQ_] = code;
  }
}

// ---------------- Kernel 2: exact top-16 by (dist, index) -------------------
// v4 (unchanged, HW-verified absmax 0.0): nibble cache in LDS (4KB/wave),
// codes streamed from global (64KB/batch, L2-resident), zero __syncthreads,
// launch_bounds(512,8) -> 4 blocks/CU = 32 waves/CU.
// Pass 1: distances ONCE, cache dc=min(d,15) nibbles, histogram
// rc=med3(d-8,0,7). Threshold r in [1,6] -> exact n_lt, t in [9,14];
// pass 3 re-reads nibbles with pair-ordered ballot compaction.
// r in {0,7} (prob ~0) -> exact cold fallback (global re-scan, 3-pass).
__global__ __launch_bounds__(512, 8) void select_kernel(
    const uint64_t* __restrict__ qcodes, const uint64_t* __restrict__ pcodes,
    float* __restrict__ outIdx, float* __restrict__ outDist) {
  __shared__ unsigned nib[8 * 1024];  // 32 KB: 8 waves x 4KB nibble cache
  __shared__ unsigned keybuf[8][K_];

  int tid = threadIdx.x;
  int w = tid >> 6, lane = tid & 63;
  int qg = blockIdx.x * 8 + w;  // global query id
  int bb = blockIdx.x >> 8;     // 256 blocks per batch
  const ulonglong2* pb2 = (const ulonglong2*)(pcodes + (size_t)bb * NP_);
  uint64_t qc = qcodes[qg];
  unsigned* nibw = nib + w * 1024;
  const uint64_t M = 0x00FF00FF00FF00FFull;

  // ---- Pass 1: stream codes from L2; nibble cache + merged-bin hist ----
  uint64_t cf = 0;
  unsigned accum = 0;
#pragma unroll 4
  for (int j2 = 0; j2 < 64; ++j2) {
    ulonglong2 pc = pb2[j2 * 64 + lane];  // coalesced 16B, L2-hot
    unsigned d0 = (unsigned)__popcll(qc ^ pc.x);
    unsigned d1 = (unsigned)__popcll(qc ^ pc.y);
    unsigned c0 = d0 < 15u ? d0 : 15u;
    unsigned c1 = d1 < 15u ? d1 : 15u;
    accum |= (c0 | (c1 << 4)) << (8 * (j2 & 3));
    int r0 = (int)d0 - 8; r0 = r0 < 0 ? 0 : (r0 > 7 ? 7 : r0);  // v_med3
    int r1 = (int)d1 - 8; r1 = r1 < 0 ? 0 : (r1 > 7 ? 7 : r1);
    cf += (1ull << (r0 << 3)) + (1ull << (r1 << 3));  // bytes <=128: safe
    if ((j2 & 3) == 3) {
      nibw[lane + 64 * (j2 >> 2)] = accum;  // bank lane%32: 2-way, free
      accum = 0;
    }
  }
  uint64_t e = cf & M, o = (cf >> 8) & M;
#pragma unroll
  for (int s = 1; s < 64; s <<= 1) {
    e += __shfl_xor(e, s);
    o += __shfl_xor(o, s);
  }

  int t = 0;
  unsigned n_lt = 0;
  int rfound = -1;
  {
    unsigned cum = 0;
#pragma unroll
    for (int r = 0; r < 8; ++r) {
      unsigned c = (unsigned)(((r & 1) ? o : e) >> ((r >> 1) * 16)) & 0xFFFFu;
      if (rfound < 0 && cum + c >= K_) { rfound = r; t = 8 + r; n_lt = cum; }
      cum += c;
    }
  }
  uint64_t lmask = (1ull << lane) - 1;

  if (rfound >= 1 && rfound <= 6) {
    // ---- Pass 3 (fast): LDS nibble scan, pair-ordered collection ----
    unsigned r_need = K_ - n_lt;
    unsigned cl = 0, ce = 0;
    unsigned ut = (unsigned)t;
#pragma unroll 4
    for (int k = 0; k < 16; ++k) {
      unsigned dw = nibw[lane + 64 * k];
#pragma unroll
      for (int b = 0; b < 4; ++b) {
        unsigned d0 = (dw >> (8 * b)) & 0xFu;
        unsigned d1 = (dw >> (8 * b + 4)) & 0xFu;
        int p0 = (4 * k + b) * 128 + 2 * lane;
        uint64_t m0 = __ballot(d0 < ut);
        uint64_t m1 = __ballot(d1 < ut);
        if (m0 | m1) {
          unsigned base = cl + (unsigned)__popcll(m0 & lmask) +
                          (unsigned)__popcll(m1 & lmask);
          if (d0 < ut) keybuf[w][base] = (d0 << 13) | (unsigned)p0;
          if (d1 < ut)
            keybuf[w][base + (unsigned)((m0 >> lane) & 1)] =
                (d1 << 13) | (unsigned)(p0 + 1);
          cl += (unsigned)__popcll(m0) + (unsigned)__popcll(m1);
        }
        if (ce < r_need) {  // wave-uniform: skipped once eq quota filled
          uint64_t q0 = __ballot(d0 == ut);
          uint64_t q1 = __ballot(d1 == ut);
          if (q0 | q1) {
            unsigned b2 = ce + (unsigned)__popcll(q0 & lmask) +
                          (unsigned)__popcll(q1 & lmask);
            unsigned pos1 = b2 + (unsigned)((q0 >> lane) & 1);
            if (d0 == ut && b2 < r_need)
              keybuf[w][n_lt + b2] = (ut << 13) | (unsigned)p0;
            if (d1 == ut && pos1 < r_need)
              keybuf[w][n_lt + pos1] = (ut << 13) | (unsigned)(p0 + 1);
            ce += (unsigned)__popcll(q0) + (unsigned)__popcll(q1);
          }
        }
      }
    }
  } else {
    // ---- Exact fallback (cold, prob ~0): global re-scan, 3-pass ----
    const uint64_t* pbl = pcodes + (size_t)bb * NP_;
    uint64_t c8 = 0;
#pragma unroll 4
    for (int j = 0; j < 64; ++j) {
      ulonglong2 pc = pb2[j * 64 + lane];
      int d0 = __popcll(qc ^ pc.x);
      int d1 = __popcll(qc ^ pc.y);
      c8 += (1ull << (d0 & 56)) + (1ull << (d1 & 56));  // (d>>3)*8 == d&56
    }
    uint64_t e2 = c8 & M, o2 = (c8 >> 8) & M;
#pragma unroll
    for (int s = 1; s < 64; s <<= 1) {
      e2 += __shfl_xor(e2, s);
      o2 += __shfl_xor(o2, s);
    }
    int Bb = 0;
    unsigned nbefore = 0, cum = 0;
    bool found = false;
#pragma unroll
    for (int k2 = 0; k2 < 6; ++k2) {
      unsigned c = (unsigned)(((k2 & 1) ? o2 : e2) >> ((k2 >> 1) * 16)) & 0xFFFFu;
      if (!found && cum + c >= K_) { Bb = k2; nbefore = cum; found = true; }
      cum += c;
    }
    int base = Bb * 8;
    uint64_t cff = 0;
#pragma unroll 4
    for (int j = 0; j < 64; ++j) {
      ulonglong2 pc = pb2[j * 64 + lane];
      unsigned r0 = (unsigned)(__popcll(qc ^ pc.x) - base);
      unsigned r1 = (unsigned)(__popcll(qc ^ pc.y) - base);
      if (r0 < 8u) cff += 1ull << (r0 << 3);
      if (r1 < 8u) cff += 1ull << (r1 << 3);
    }
    uint64_t ef = cff & M, of = (cff >> 8) & M;
#pragma unroll
    for (int s = 1; s < 64; s <<= 1) {
      ef += __shfl_xor(ef, s);
      of += __shfl_xor(of, s);
    }
    unsigned cum2 = nbefore;
    bool f2 = false;
#pragma unroll
    for (int r = 0; r < 8; ++r) {
      unsigned c = (unsigned)(((r & 1) ? of : ef) >> ((r >> 1) * 16)) & 0xFFFFu;
      if (!f2 && cum2 + c >= K_) { t = base + r; n_lt = cum2; f2 = true; }
      cum2 += c;
    }
    unsigned r_need = K_ - n_lt;
    unsigned cl = 0, ce = 0;
    for (int j = 0; j < 128; ++j) {
      int p = j * 64 + lane;
      int d = __popcll(qc ^ pbl[p]);
      if (__any(d <= t)) {
        bool blt = (d < t), beq = (d == t);
        uint64_t mlt = __ballot(blt), meq = __ballot(beq);
        if (blt)
          keybuf[w][cl + (unsigned)__popcll(mlt & lmask)] =
              ((unsigned)d << 13) | (unsigned)p;
        if (beq) {
          unsigned pos = ce + (unsigned)__popcll(meq & lmask);
          if (pos < r_need)
            keybuf[w][n_lt + pos] = ((unsigned)d << 13) | (unsigned)p;
        }
        cl += (unsigned)__popcll(mlt);
        ce += (unsigned)__popcll(meq);
      }
    }
  }

  // ---- rank-sort the 16 keys (distinct: idx embedded) and emit ----
  // keybuf[w] written and read by the SAME wave: no block sync needed.
  if (lane < K_) {
    unsigned my = keybuf[w][lane];
    int rank = 0;
#pragma unroll
    for (int jj = 0; jj < K_; ++jj) rank += (keybuf[w][jj] < my) ? 1 : 0;
    int off = qg * K_ + rank;
    outIdx[off]  = (float)(my & 8191u);  // index
    outDist[off] = (float)(my >> 13);    // distance
  }
}

extern "C" void kernel_launch(void* const* d_in, const int* in_sizes, int n_in,
                              void* d_out, int out_size, void* d_ws, size_t ws_size,
                              hipStream_t stream) {
  const float* qp   = (const float*)d_in[0];
  const float* pp   = (const float*)d_in[1];
  const float* proj = (const float*)d_in[2];
  // d_in[3] is k (always 16) — hardcoded.

  uint64_t* pcodes = (uint64_t*)d_ws;            // B*NP u64
  uint64_t* qcodes = pcodes + (size_t)B_ * NP_;  // B*NQ u64

  float* outIdx  = (float*)d_out;                   // B*NQ*K indices (as float)
  float* outDist = outIdx + (size_t)B_ * NQ_ * K_;  // B*NQ*K distances

  int total_vecs = B_ * (NQ_ + NP_);  // 40960
  hash_kernel<<<total_vecs / 64, 512, 0, stream>>>(qp, pp, proj, qcodes, pcodes);
  select_kernel<<<B_ * NQ_ / 8, 512, 0, stream>>>(qcodes, pcodes, outIdx, outDist);
}